// Round 5
// baseline (336.977 us; speedup 1.0000x reference)
//
#include <hip/hip_runtime.h>
#include <cstdint>
#include <cstddef>

// ---------------- problem constants ----------------
#define DD 1024          // feature dim (= K = N per GEMM)
#define TT 8192          // sequence length
#define BB 4             // batch
#define MM (BB*TT)       // 32768 rows
#define NCHUNK 64        // scan chunks over T
#define CLEN 128         // chunk length (NCHUNK*CLEN == TT)
#define EPS 1e-5f
#define NK2 16           // K tiles of 64 (DD/64)

typedef __attribute__((ext_vector_type(8))) short bf16x8;
typedef __attribute__((ext_vector_type(4))) float f32x4;

// ---------------- bf16 helpers (bit-level, RNE) ----------------
__device__ __forceinline__ float bf2f(unsigned short b) {
  union { unsigned int u; float f; } c; c.u = ((unsigned int)b) << 16; return c.f;
}
__device__ __forceinline__ unsigned short f2bf(float f) {
  union { float f; unsigned int u; } c; c.f = f;
  unsigned int lsb = (c.u >> 16) & 1u;
  c.u += 0x7fffu + lsb;
  return (unsigned short)(c.u >> 16);
}

// ---------------- async global->LDS (16B per lane) ----------------
__device__ __forceinline__ void gload16(const void* gsrc, void* ldst) {
  __builtin_amdgcn_global_load_lds(
      (const __attribute__((address_space(1))) unsigned int*)gsrc,
      (__attribute__((address_space(3))) unsigned int*)ldst, 16, 0, 0);
}

// LDS slot swizzle over [R][32]-packed k-half tiles: row = 64B = 4 slots of
// 16B; phys_slot = log_slot ^ ((row>>1)&3). Verified 0 bank conflicts (R3/R4).
#define SWZ(row) (((row) >> 1) & 3)

// Stage an R x 32 bf16 k-half from row-major (ld=1024) global into LDS,
// inverse-swizzled SOURCE (LDS dest linear per gload_lds constraint).
// R=256 -> 2 instr/wave, R=128 -> 1 instr/wave (512 threads).
template<int R>
__device__ __forceinline__ void stageT(const unsigned short* __restrict__ g,
                                       size_t row0, int k0,
                                       unsigned short* lds, int tid) {
#pragma unroll
  for (int l = 0; l < R / 128; ++l) {
    int u16 = l * 512 + tid;          // 16B unit index in tile
    int row = u16 >> 2;
    int sp  = u16 & 3;                // physical slot
    int sl  = sp ^ SWZ(row);          // logical (global) slot
    const unsigned short* src = g + (row0 + (size_t)row) * DD + k0 + sl * 8;
    gload16(src, (char*)lds + (size_t)u16 * 16);
  }
}

// Read one MFMA A/B fragment (16 rows x 8 k) from a swizzled k-half tile.
__device__ __forceinline__ bf16x8 ldsfrag(const unsigned short* lds, int row, int sl) {
  int sp = sl ^ SWZ(row);
  return *(const bf16x8*)&lds[row * 32 + sp * 8];
}

#define MFMA16(a, b, c) __builtin_amdgcn_mfma_f32_16x16x32_bf16((a), (b), (c), 0, 0, 0)

// Half-boundary sync: per-wave counted vmcnt BEFORE the barrier makes the
// landing guarantee cross-wave sound. Never 0 in steady state.
template<int N>
__device__ __forceinline__ void half_sync() {
  __builtin_amdgcn_sched_barrier(0);
  if constexpr (N == 8)      asm volatile("s_waitcnt vmcnt(8)" ::: "memory");
  else if constexpr (N == 4) asm volatile("s_waitcnt vmcnt(4)" ::: "memory");
  else                       asm volatile("s_waitcnt vmcnt(0)" ::: "memory");
  __builtin_amdgcn_s_barrier();
  __builtin_amdgcn_sched_barrier(0);
}

// ---------------- kernel 1: cast weights to bf16 ----------------
__global__ __launch_bounds__(256) void cast_weights(
    const float* __restrict__ wg, const float* __restrict__ wv,
    const float* __restrict__ wo,
    unsigned short* __restrict__ owg, unsigned short* __restrict__ owv,
    unsigned short* __restrict__ owo) {
  int i = blockIdx.x * 256 + threadIdx.x;   // over float4 units; 3*262144 total
  const float* src; unsigned short* dst; int off;
  if (i < 262144)       { src = wg; dst = owg; off = i; }
  else if (i < 524288)  { src = wv; dst = owv; off = i - 262144; }
  else                  { src = wo; dst = owo; off = i - 524288; }
  float4 v = ((const float4*)src)[off];
  ushort4 o;
  o.x = f2bf(v.x); o.y = f2bf(v.y); o.z = f2bf(v.z); o.w = f2bf(v.w);
  ((ushort4*)dst)[off] = o;
}

// ---------------- kernel 2: LayerNorm -> bf16 ----------------
__global__ __launch_bounds__(256) void ln_kernel(
    const float* __restrict__ x, const float* __restrict__ gamma,
    const float* __restrict__ beta, unsigned short* __restrict__ normed) {
  size_t row = blockIdx.x;
  int tid = threadIdx.x, lane = tid & 63, wid = tid >> 6;
  float4 v = ((const float4*)(x + row * DD))[tid];
  float s = v.x + v.y + v.z + v.w;
  float q = v.x * v.x + v.y * v.y + v.z * v.z + v.w * v.w;
#pragma unroll
  for (int off = 32; off; off >>= 1) {
    s += __shfl_down(s, off);
    q += __shfl_down(q, off);
  }
  __shared__ float rs[4], rq[4];
  if (lane == 0) { rs[wid] = s; rq[wid] = q; }
  __syncthreads();
  float ts = rs[0] + rs[1] + rs[2] + rs[3];
  float tq = rq[0] + rq[1] + rq[2] + rq[3];
  float mu  = ts * (1.0f / DD);
  float var = tq * (1.0f / DD) - mu * mu;
  float rstd = rsqrtf(var + EPS);
  float4 gm = ((const float4*)gamma)[tid];
  float4 bt = ((const float4*)beta)[tid];
  ushort4 o;
  o.x = f2bf((v.x - mu) * rstd * gm.x + bt.x);
  o.y = f2bf((v.y - mu) * rstd * gm.y + bt.y);
  o.z = f2bf((v.z - mu) * rstd * gm.z + bt.z);
  o.w = f2bf((v.w - mu) * rstd * gm.w + bt.w);
  ((ushort4*)normed)[row * (DD / 4) + tid] = o;
}

// ---------------- kernel 3: fused gate/value GEMM -> u (+ chunk sums) ------
// 256x128 tile, BK=64, 8 waves (2M x 4N), wave owns 128x32 of BOTH outputs.
// 4-slot half-ring, 3 halves in flight, vmcnt(8) steady state, 2 barriers/K-tile.
__global__ __launch_bounds__(512, 2) void gemm_gv(
    const unsigned short* __restrict__ normed,
    const unsigned short* __restrict__ wg, const unsigned short* __restrict__ wv,
    const float* __restrict__ bg, const float* __restrict__ bv,
    unsigned short* __restrict__ u, float* __restrict__ sums) {
  __shared__ unsigned short As[2][2][256 * 32];   // [buf][khalf] 64 KiB
  __shared__ unsigned short Bgs[2][2][128 * 32];  // 32 KiB
  __shared__ unsigned short Bvs[2][2][128 * 32];  // 32 KiB
  int tid = threadIdx.x, lane = tid & 63, wid = tid >> 6;
  int wm = wid >> 2, wn = wid & 3;         // 2 M-groups x 4 N-groups
  int nwg = gridDim.x;                     // 1024, %8==0
  int swz = (blockIdx.x & 7) * (nwg >> 3) + (blockIdx.x >> 3);
  int bx = swz >> 3;                       // M block (128); by fastest ->
  int by = swz & 7;                        // XCD owns contiguous bx chunk
  size_t m0 = (size_t)bx * 256;
  int n0 = by * 128;

  f32x4 accg[8][2], accv[8][2];
#pragma unroll
  for (int a = 0; a < 8; ++a)
#pragma unroll
    for (int b = 0; b < 2; ++b) {
      accg[a][b] = (f32x4){0.f, 0.f, 0.f, 0.f};
      accv[a][b] = (f32x4){0.f, 0.f, 0.f, 0.f};
    }

  // stage half h (= 4 vmem instr/wave) into ring slot [ (h>>1)&1 ][ h&1 ]
  auto STAGE = [&](int h) {
    int t = h >> 1, kh = h & 1, k0 = t * 64 + kh * 32;
    stageT<256>(normed, m0, k0, As[t & 1][kh], tid);
    stageT<128>(wg, (size_t)n0, k0, Bgs[t & 1][kh], tid);
    stageT<128>(wv, (size_t)n0, k0, Bvs[t & 1][kh], tid);
  };

  // prologue: 3 halves in flight
  STAGE(0); STAGE(1); STAGE(2);
  half_sync<8>();   // half 0 landed (1,2 in flight)

  int r = lane & 15, q = lane >> 4;
  bf16x8 af[8], b0, b1;
  for (int t = 0; t < NK2; ++t) {
    int buf = t & 1;
    // ---- p0: kh0, gate ----
#pragma unroll
    for (int mi = 0; mi < 8; ++mi)
      af[mi] = ldsfrag(As[buf][0], wm * 128 + mi * 16 + r, q);
    b0 = ldsfrag(Bgs[buf][0], wn * 32 + r, q);
    b1 = ldsfrag(Bgs[buf][0], wn * 32 + 16 + r, q);
    if (t < NK2 - 1) STAGE(2 * t + 3);
    __builtin_amdgcn_s_setprio(1);
#pragma unroll
    for (int mi = 0; mi < 8; ++mi) {
      accg[mi][0] = MFMA16(af[mi], b0, accg[mi][0]);
      accg[mi][1] = MFMA16(af[mi], b1, accg[mi][1]);
    }
    __builtin_amdgcn_s_setprio(0);
    // ---- p1: kh0, value ----
    b0 = ldsfrag(Bvs[buf][0], wn * 32 + r, q);
    b1 = ldsfrag(Bvs[buf][0], wn * 32 + 16 + r, q);
    __builtin_amdgcn_s_setprio(1);
#pragma unroll
    for (int mi = 0; mi < 8; ++mi) {
      accv[mi][0] = MFMA16(af[mi], b0, accv[mi][0]);
      accv[mi][1] = MFMA16(af[mi], b1, accv[mi][1]);
    }
    __builtin_amdgcn_s_setprio(0);
    if (t < NK2 - 1) half_sync<8>();   // half 2t+1 landed
    else             half_sync<0>();
    // ---- p2: kh1, value ----
#pragma unroll
    for (int mi = 0; mi < 8; ++mi)
      af[mi] = ldsfrag(As[buf][1], wm * 128 + mi * 16 + r, q);
    b0 = ldsfrag(Bvs[buf][1], wn * 32 + r, q);
    b1 = ldsfrag(Bvs[buf][1], wn * 32 + 16 + r, q);
    if (t < NK2 - 2) STAGE(2 * t + 4);
    __builtin_amdgcn_s_setprio(1);
#pragma unroll
    for (int mi = 0; mi < 8; ++mi) {
      accv[mi][0] = MFMA16(af[mi], b0, accv[mi][0]);
      accv[mi][1] = MFMA16(af[mi], b1, accv[mi][1]);
    }
    __builtin_amdgcn_s_setprio(0);
    // ---- p3: kh1, gate ----
    b0 = ldsfrag(Bgs[buf][1], wn * 32 + r, q);
    b1 = ldsfrag(Bgs[buf][1], wn * 32 + 16 + r, q);
    __builtin_amdgcn_s_setprio(1);
#pragma unroll
    for (int mi = 0; mi < 8; ++mi) {
      accg[mi][0] = MFMA16(af[mi], b0, accg[mi][0]);
      accg[mi][1] = MFMA16(af[mi], b1, accg[mi][1]);
    }
    __builtin_amdgcn_s_setprio(0);
    if (t < NK2 - 2)      half_sync<8>();   // half 2t+2 landed
    else if (t == NK2 - 2) half_sync<4>();
    // t == NK2-1: fall through to epilogue (all landed at half_sync<0>)
  }

  // epilogue: u = (2*sigmoid(g)-1)*v, plus fused per-chunk partial sums.
  // C/D layout col=lane&15, row=(lane>>4)*4+j  [m89/m91 verified]
  float psum[2] = {0.f, 0.f};
#pragma unroll
  for (int mi = 0; mi < 8; ++mi)
#pragma unroll
    for (int ni = 0; ni < 2; ++ni) {
      int e = n0 + wn * 32 + ni * 16 + r;
      size_t rbase = m0 + wm * 128 + mi * 16 + q * 4;
      float bgv = bg[e], bvv = bv[e];
#pragma unroll
      for (int j = 0; j < 4; ++j) {
        float gp = accg[mi][ni][j] + bgv;
        float vp = accv[mi][ni][j] + bvv;
        float sg = 1.0f / (1.0f + __expf(-gp));
        float uu = (2.0f * sg - 1.0f) * vp;
        psum[ni] += uu;
        u[(rbase + j) * DD + e] = f2bf(uu);
      }
    }
#pragma unroll
  for (int ni = 0; ni < 2; ++ni) {
    psum[ni] += __shfl_xor(psum[ni], 16);
    psum[ni] += __shfl_xor(psum[ni], 32);
  }
  if (lane < 16) {
    int b = (int)(m0 >> 13);
    int ch = (int)((m0 & 8191) >> 7) + wm;
    size_t sidx = ((size_t)(b * NCHUNK + ch)) * DD + n0 + wn * 32 + lane;
    sums[sidx]      = psum[0];
    sums[sidx + 16] = psum[1];
  }
}

// ---------------- kernel 5: exclusive scan over chunk sums (in place) ------
__global__ __launch_bounds__(256) void scan_chunks(float* __restrict__ sums) {
  int b = blockIdx.x >> 2;
  int e = (blockIdx.x & 3) * 256 + threadIdx.x;
  float vals[NCHUNK];
#pragma unroll
  for (int c = 0; c < NCHUNK; ++c)
    vals[c] = sums[((size_t)(b * NCHUNK + c)) * DD + e];
  float carry = 0.f;
#pragma unroll
  for (int c = 0; c < NCHUNK; ++c) {
    float t = vals[c]; vals[c] = carry; carry += t;
  }
#pragma unroll
  for (int c = 0; c < NCHUNK; ++c)
    sums[((size_t)(b * NCHUNK + c)) * DD + e] = vals[c];
}

// ---------------- kernel 6: chunk-local scan + decay, in place ----------------
__global__ __launch_bounds__(128) void scan_final(
    unsigned short* __restrict__ u, const float* __restrict__ sums,
    const float* __restrict__ log_decay) {
  int bid = blockIdx.x;
  int half = bid & 1, chunk = (bid >> 1) & 63, b = bid >> 7;
  int e0 = half * 512 + threadIdx.x * 4;
  float alpha = log1pf(__expf(log_decay[0]));   // softplus
  float4 c = *(const float4*)(sums + ((size_t)(b * NCHUNK + chunk)) * DD + e0);
  size_t base = ((size_t)b * TT + (size_t)chunk * CLEN) * DD + e0;
#pragma unroll 4
  for (int i = 0; i < CLEN; ++i) {
    int t = chunk * CLEN + i;
    float dec = __expf(-alpha * (float)t);
    ushort4 w = *(const ushort4*)(u + base + (size_t)i * DD);
    c.x += bf2f(w.x); c.y += bf2f(w.y); c.z += bf2f(w.z); c.w += bf2f(w.w);
    ushort4 o;
    o.x = f2bf(c.x * dec); o.y = f2bf(c.y * dec);
    o.z = f2bf(c.z * dec); o.w = f2bf(c.w * dec);
    *(ushort4*)(u + base + (size_t)i * DD) = o;
  }
}

// ---------------- kernel 7: output GEMM + residual ----------------
// 256x256 tile, BK=64, 8 waves (2M x 4N), wave owns 128x64.
// Same 4-slot half-ring schedule as gemm_gv.
__global__ __launch_bounds__(512, 2) void gemm_out(
    const unsigned short* __restrict__ cmat, const unsigned short* __restrict__ wo,
    const float* __restrict__ bo, const float* __restrict__ x,
    float* __restrict__ out) {
  __shared__ unsigned short As[2][2][256 * 32];   // 64 KiB
  __shared__ unsigned short Bs[2][2][256 * 32];   // 64 KiB
  int tid = threadIdx.x, lane = tid & 63, wid = tid >> 6;
  int wm = wid >> 2, wn = wid & 3;         // 2 M-groups x 4 N-groups
  int nwg = gridDim.x;                     // 512, %8==0
  int swz = (blockIdx.x & 7) * (nwg >> 3) + (blockIdx.x >> 3);
  int bx = swz >> 2;                       // M block (128); by fastest
  int by = swz & 3;                        // N block (4)
  size_t m0 = (size_t)bx * 256;
  int n0 = by * 256;

  f32x4 acc[8][4];
#pragma unroll
  for (int a = 0; a < 8; ++a)
#pragma unroll
    for (int b = 0; b < 4; ++b) acc[a][b] = (f32x4){0.f, 0.f, 0.f, 0.f};

  auto STAGE = [&](int h) {
    int t = h >> 1, kh = h & 1, k0 = t * 64 + kh * 32;
    stageT<256>(cmat, m0, k0, As[t & 1][kh], tid);
    stageT<256>(wo, (size_t)n0, k0, Bs[t & 1][kh], tid);
  };

  STAGE(0); STAGE(1); STAGE(2);
  half_sync<8>();

  int r = lane & 15, q = lane >> 4;
  bf16x8 af[8], b0, b1;
  for (int t = 0; t < NK2; ++t) {
    int buf = t & 1;
    // ---- p0: kh0, n-halves 0,1 ----
#pragma unroll
    for (int mi = 0; mi < 8; ++mi)
      af[mi] = ldsfrag(As[buf][0], wm * 128 + mi * 16 + r, q);
    b0 = ldsfrag(Bs[buf][0], wn * 64 + r, q);
    b1 = ldsfrag(Bs[buf][0], wn * 64 + 16 + r, q);
    if (t < NK2 - 1) STAGE(2 * t + 3);
    __builtin_amdgcn_s_setprio(1);
#pragma unroll
    for (int mi = 0; mi < 8; ++mi) {
      acc[mi][0] = MFMA16(af[mi], b0, acc[mi][0]);
      acc[mi][1] = MFMA16(af[mi], b1, acc[mi][1]);
    }
    __builtin_amdgcn_s_setprio(0);
    // ---- p1: kh0, n-halves 2,3 ----
    b0 = ldsfrag(Bs[buf][0], wn * 64 + 32 + r, q);
    b1 = ldsfrag(Bs[buf][0], wn * 64 + 48 + r, q);
    __builtin_amdgcn_s_setprio(1);
#pragma unroll
    for (int mi = 0; mi < 8; ++mi) {
      acc[mi][2] = MFMA16(af[mi], b0, acc[mi][2]);
      acc[mi][3] = MFMA16(af[mi], b1, acc[mi][3]);
    }
    __builtin_amdgcn_s_setprio(0);
    if (t < NK2 - 1) half_sync<8>();
    else             half_sync<0>();
    // ---- p2: kh1, n-halves 0,1 ----
#pragma unroll
    for (int mi = 0; mi < 8; ++mi)
      af[mi] = ldsfrag(As[buf][1], wm * 128 + mi * 16 + r, q);
    b0 = ldsfrag(Bs[buf][1], wn * 64 + r, q);
    b1 = ldsfrag(Bs[buf][1], wn * 64 + 16 + r, q);
    if (t < NK2 - 2) STAGE(2 * t + 4);
    __builtin_amdgcn_s_setprio(1);
#pragma unroll
    for (int mi = 0; mi < 8; ++mi) {
      acc[mi][0] = MFMA16(af[mi], b0, acc[mi][0]);
      acc[mi][1] = MFMA16(af[mi], b1, acc[mi][1]);
    }
    __builtin_amdgcn_s_setprio(0);
    // ---- p3: kh1, n-halves 2,3 ----
    b0 = ldsfrag(Bs[buf][1], wn * 64 + 32 + r, q);
    b1 = ldsfrag(Bs[buf][1], wn * 64 + 48 + r, q);
    __builtin_amdgcn_s_setprio(1);
#pragma unroll
    for (int mi = 0; mi < 8; ++mi) {
      acc[mi][2] = MFMA16(af[mi], b0, acc[mi][2]);
      acc[mi][3] = MFMA16(af[mi], b1, acc[mi][3]);
    }
    __builtin_amdgcn_s_setprio(0);
    if (t < NK2 - 2)       half_sync<8>();
    else if (t == NK2 - 2) half_sync<4>();
  }

#pragma unroll
  for (int mi = 0; mi < 8; ++mi)
#pragma unroll
    for (int nq = 0; nq < 4; ++nq) {
      int e = n0 + wn * 64 + nq * 16 + r;
      size_t rbase = m0 + wm * 128 + mi * 16 + q * 4;
      float bov = bo[e];
#pragma unroll
      for (int j = 0; j < 4; ++j) {
        size_t idx = (rbase + j) * DD + e;
        out[idx] = x[idx] + bov + acc[mi][nq][j];
      }
    }
}

// ---------------- launch ----------------
extern "C" void kernel_launch(void* const* d_in, const int* in_sizes, int n_in,
                              void* d_out, int out_size, void* d_ws, size_t ws_size,
                              hipStream_t stream) {
  const float* x     = (const float*)d_in[0];
  const float* gamma = (const float*)d_in[1];
  const float* beta  = (const float*)d_in[2];
  const float* Wg    = (const float*)d_in[3];
  const float* bg    = (const float*)d_in[4];
  const float* Wv    = (const float*)d_in[5];
  const float* bv    = (const float*)d_in[6];
  const float* Wo    = (const float*)d_in[7];
  const float* bo    = (const float*)d_in[8];
  const float* ldcy  = (const float*)d_in[9];
  float* out = (float*)d_out;

  char* ws = (char*)d_ws;
  // layout: normed bf16 (64MiB) | u/c bf16 (64MiB) | Wg,Wv,Wo bf16 (3x2MiB) | sums f32 (1MiB)
  unsigned short* normed = (unsigned short*)ws;
  unsigned short* u      = (unsigned short*)(ws + (size_t)67108864);
  unsigned short* wgb    = (unsigned short*)(ws + (size_t)134217728);
  unsigned short* wvb    = wgb + 1048576;
  unsigned short* wob    = wvb + 1048576;
  float* sums            = (float*)(ws + (size_t)134217728 + (size_t)3 * 2097152);

  cast_weights<<<3072, 256, 0, stream>>>(Wg, Wv, Wo, wgb, wvb, wob);
  ln_kernel<<<MM, 256, 0, stream>>>(x, gamma, beta, normed);
  gemm_gv<<<dim3(MM / 256 * (DD / 128)), 512, 0, stream>>>(normed, wgb, wvb, bg, bv, u, sums);
  scan_chunks<<<BB * (DD / 256), 256, 0, stream>>>(sums);
  scan_final<<<BB * NCHUNK * 2, 128, 0, stream>>>(u, sums, ldcy);
  gemm_out<<<dim3(MM / 256 * (DD / 256)), 512, 0, stream>>>(u, wob, bo, x, out);
}

// Round 6
// 321.274 us; speedup vs baseline: 1.0489x; 1.0489x over previous
//
#include <hip/hip_runtime.h>
#include <cstdint>
#include <cstddef>

// ---------------- problem constants ----------------
#define DD 1024          // feature dim (= K = N per GEMM)
#define TT 8192          // sequence length
#define BB 4             // batch
#define MM (BB*TT)       // 32768 rows
#define NCHUNK 64        // scan chunks over T
#define CLEN 128         // chunk length (NCHUNK*CLEN == TT)
#define EPS 1e-5f
#define NK2 16           // K tiles of 64 (DD/64)

typedef __attribute__((ext_vector_type(8))) short bf16x8;
typedef __attribute__((ext_vector_type(4))) float f32x4;

// ---------------- bf16 helpers (bit-level, RNE) ----------------
__device__ __forceinline__ float bf2f(unsigned short b) {
  union { unsigned int u; float f; } c; c.u = ((unsigned int)b) << 16; return c.f;
}
__device__ __forceinline__ unsigned short f2bf(float f) {
  union { float f; unsigned int u; } c; c.f = f;
  unsigned int lsb = (c.u >> 16) & 1u;
  c.u += 0x7fffu + lsb;
  return (unsigned short)(c.u >> 16);
}

// ---------------- async global->LDS (16B per lane) ----------------
__device__ __forceinline__ void gload16(const void* gsrc, void* ldst) {
  __builtin_amdgcn_global_load_lds(
      (const __attribute__((address_space(1))) unsigned int*)gsrc,
      (__attribute__((address_space(3))) unsigned int*)ldst, 16, 0, 0);
}

// LDS slot swizzle over [R][32]-packed k-half tiles: row = 64B = 4 slots of
// 16B; phys_slot = log_slot ^ ((row>>1)&3). Verified 0 bank conflicts (R3/R4).
#define SWZ(row) (((row) >> 1) & 3)

// Read one MFMA A/B fragment (16 rows x 8 k) from a swizzled k-half tile.
__device__ __forceinline__ bf16x8 ldsfrag(const unsigned short* lds, int row, int sl) {
  int sp = sl ^ SWZ(row);
  return *(const bf16x8*)&lds[row * 32 + sp * 8];
}

#define MFMA16(a, b, c) __builtin_amdgcn_mfma_f32_16x16x32_bf16((a), (b), (c), 0, 0, 0)

#define VMCNT4 asm volatile("s_waitcnt vmcnt(4)" ::: "memory")
#define VMCNT0 asm volatile("s_waitcnt vmcnt(0)" ::: "memory")
#define BAR    __builtin_amdgcn_s_barrier()

// ---------------- kernel 1: cast weights to bf16 ----------------
__global__ __launch_bounds__(256) void cast_weights(
    const float* __restrict__ wg, const float* __restrict__ wv,
    const float* __restrict__ wo,
    unsigned short* __restrict__ owg, unsigned short* __restrict__ owv,
    unsigned short* __restrict__ owo) {
  int i = blockIdx.x * 256 + threadIdx.x;   // over float4 units; 3*262144 total
  const float* src; unsigned short* dst; int off;
  if (i < 262144)       { src = wg; dst = owg; off = i; }
  else if (i < 524288)  { src = wv; dst = owv; off = i - 262144; }
  else                  { src = wo; dst = owo; off = i - 524288; }
  float4 v = ((const float4*)src)[off];
  ushort4 o;
  o.x = f2bf(v.x); o.y = f2bf(v.y); o.z = f2bf(v.z); o.w = f2bf(v.w);
  ((ushort4*)dst)[off] = o;
}

// ---------------- kernel 2: LayerNorm -> bf16 ----------------
__global__ __launch_bounds__(256) void ln_kernel(
    const float* __restrict__ x, const float* __restrict__ gamma,
    const float* __restrict__ beta, unsigned short* __restrict__ normed) {
  size_t row = blockIdx.x;
  int tid = threadIdx.x, lane = tid & 63, wid = tid >> 6;
  float4 v = ((const float4*)(x + row * DD))[tid];
  float s = v.x + v.y + v.z + v.w;
  float q = v.x * v.x + v.y * v.y + v.z * v.z + v.w * v.w;
#pragma unroll
  for (int off = 32; off; off >>= 1) {
    s += __shfl_down(s, off);
    q += __shfl_down(q, off);
  }
  __shared__ float rs[4], rq[4];
  if (lane == 0) { rs[wid] = s; rq[wid] = q; }
  __syncthreads();
  float ts = rs[0] + rs[1] + rs[2] + rs[3];
  float tq = rq[0] + rq[1] + rq[2] + rq[3];
  float mu  = ts * (1.0f / DD);
  float var = tq * (1.0f / DD) - mu * mu;
  float rstd = rsqrtf(var + EPS);
  float4 gm = ((const float4*)gamma)[tid];
  float4 bt = ((const float4*)beta)[tid];
  ushort4 o;
  o.x = f2bf((v.x - mu) * rstd * gm.x + bt.x);
  o.y = f2bf((v.y - mu) * rstd * gm.y + bt.y);
  o.z = f2bf((v.z - mu) * rstd * gm.z + bt.z);
  o.w = f2bf((v.w - mu) * rstd * gm.w + bt.w);
  ((ushort4*)normed)[row * (DD / 4) + tid] = o;
}

// ---------------- kernel 3: fused gate/value GEMM -> u (+ chunk sums) ------
// 256x128 tile, BK=64, 8 waves (2M x 4N), wave owns 128x32 of BOTH outputs.
// R4 skeleton (4 phases/K-tile, 2 barriers/phase, vmcnt(4) at p1/p3 ends),
// but NO lgkm drains / sched_barrier pins (compiler emits fine lgkmcnt),
// and staging addresses hoisted out of the loop.
__global__ __launch_bounds__(512, 2) void gemm_gv(
    const unsigned short* __restrict__ normed,
    const unsigned short* __restrict__ wg, const unsigned short* __restrict__ wv,
    const float* __restrict__ bg, const float* __restrict__ bv,
    unsigned short* __restrict__ u, float* __restrict__ sums) {
  __shared__ unsigned short As[2][2][256 * 32];   // [buf][khalf] 64 KiB
  __shared__ unsigned short Bgs[2][2][128 * 32];  // 32 KiB
  __shared__ unsigned short Bvs[2][2][128 * 32];  // 32 KiB
  int tid = threadIdx.x, lane = tid & 63, wid = tid >> 6;
  int wm = wid >> 2, wn = wid & 3;         // 2 M-groups x 4 N-groups
  int nwg = gridDim.x;                     // 1024, %8==0
  int swz = (blockIdx.x & 7) * (nwg >> 3) + (blockIdx.x >> 3);
  int bx = swz >> 3;                       // M block (128); by fastest ->
  int by = swz & 7;                        // XCD owns contiguous bx chunk
  size_t m0 = (size_t)bx * 256;
  int n0 = by * 128;

  // per-thread staging invariants: half h source = base + h*32 elements
  int rowq = tid >> 2, sp = tid & 3;
  int sl0 = sp ^ SWZ(rowq);                // SWZ(rowq+128) == SWZ(rowq)
  const unsigned short* eA0 = normed + (m0 + rowq) * DD + sl0 * 8;
  const unsigned short* eA1 = normed + (m0 + 128 + rowq) * DD + sl0 * 8;
  const unsigned short* eBg = wg + ((size_t)n0 + rowq) * DD + sl0 * 8;
  const unsigned short* eBv = wv + ((size_t)n0 + rowq) * DD + sl0 * 8;

  auto SA = [&](int h) {   // 2 loads: A half-tile h
    char* d = (char*)&As[(h >> 1) & 1][h & 1][0] + tid * 16;
    gload16(eA0 + h * 32, d);
    gload16(eA1 + h * 32, d + 8192);
  };
  auto SB = [&](int h) {   // 2 loads: Bg + Bv half-tile h
    gload16(eBg + h * 32, (char*)&Bgs[(h >> 1) & 1][h & 1][0] + tid * 16);
    gload16(eBv + h * 32, (char*)&Bvs[(h >> 1) & 1][h & 1][0] + tid * 16);
  };

  f32x4 accg[8][2], accv[8][2];
#pragma unroll
  for (int a = 0; a < 8; ++a)
#pragma unroll
    for (int b = 0; b < 2; ++b) {
      accg[a][b] = (f32x4){0.f, 0.f, 0.f, 0.f};
      accv[a][b] = (f32x4){0.f, 0.f, 0.f, 0.f};
    }

  // prologue: stage tile 0 (h=0,1), wait h=0
  SA(0); SB(0); SA(1); SB(1);
  VMCNT4;
  BAR;

  int r = lane & 15, q = lane >> 4;
  for (int t = 0; t < NK2; ++t) {
    int buf = t & 1;
    bool more = (t + 1 < NK2);
    bf16x8 af[8], b0, b1;
    // ---- p0: kh0, gate ----
    b0 = ldsfrag(Bgs[buf][0], wn * 32 + r, q);
    b1 = ldsfrag(Bgs[buf][0], wn * 32 + 16 + r, q);
#pragma unroll
    for (int mi = 0; mi < 8; ++mi)
      af[mi] = ldsfrag(As[buf][0], wm * 128 + mi * 16 + r, q);
    if (more) SA(2 * t + 2);
    BAR;
    __builtin_amdgcn_s_setprio(1);
#pragma unroll
    for (int mi = 0; mi < 8; ++mi) {
      accg[mi][0] = MFMA16(af[mi], b0, accg[mi][0]);
      accg[mi][1] = MFMA16(af[mi], b1, accg[mi][1]);
    }
    __builtin_amdgcn_s_setprio(0);
    BAR;
    // ---- p1: kh0, value (A reused) ----
    b0 = ldsfrag(Bvs[buf][0], wn * 32 + r, q);
    b1 = ldsfrag(Bvs[buf][0], wn * 32 + 16 + r, q);
    if (more) SB(2 * t + 2);
    BAR;
    __builtin_amdgcn_s_setprio(1);
#pragma unroll
    for (int mi = 0; mi < 8; ++mi) {
      accv[mi][0] = MFMA16(af[mi], b0, accv[mi][0]);
      accv[mi][1] = MFMA16(af[mi], b1, accv[mi][1]);
    }
    __builtin_amdgcn_s_setprio(0);
    if (more) VMCNT4; else VMCNT0;   // kh1 of tile t landed
    BAR;
    // ---- p2: kh1, value ----
    b0 = ldsfrag(Bvs[buf][1], wn * 32 + r, q);
    b1 = ldsfrag(Bvs[buf][1], wn * 32 + 16 + r, q);
#pragma unroll
    for (int mi = 0; mi < 8; ++mi)
      af[mi] = ldsfrag(As[buf][1], wm * 128 + mi * 16 + r, q);
    if (more) SA(2 * t + 3);
    BAR;
    __builtin_amdgcn_s_setprio(1);
#pragma unroll
    for (int mi = 0; mi < 8; ++mi) {
      accv[mi][0] = MFMA16(af[mi], b0, accv[mi][0]);
      accv[mi][1] = MFMA16(af[mi], b1, accv[mi][1]);
    }
    __builtin_amdgcn_s_setprio(0);
    BAR;
    // ---- p3: kh1, gate (A reused) ----
    b0 = ldsfrag(Bgs[buf][1], wn * 32 + r, q);
    b1 = ldsfrag(Bgs[buf][1], wn * 32 + 16 + r, q);
    if (more) SB(2 * t + 3);
    BAR;
    __builtin_amdgcn_s_setprio(1);
#pragma unroll
    for (int mi = 0; mi < 8; ++mi) {
      accg[mi][0] = MFMA16(af[mi], b0, accg[mi][0]);
      accg[mi][1] = MFMA16(af[mi], b1, accg[mi][1]);
    }
    __builtin_amdgcn_s_setprio(0);
    if (more) VMCNT4;                // kh0 of tile t+1 landed
    BAR;
  }

  // epilogue: u = (2*sigmoid(g)-1)*v, plus fused per-chunk partial sums.
  // C/D layout col=lane&15, row=(lane>>4)*4+j  [m89/m91 verified]
  float psum[2] = {0.f, 0.f};
#pragma unroll
  for (int mi = 0; mi < 8; ++mi)
#pragma unroll
    for (int ni = 0; ni < 2; ++ni) {
      int e = n0 + wn * 32 + ni * 16 + r;
      size_t rbase = m0 + wm * 128 + mi * 16 + q * 4;
      float bgv = bg[e], bvv = bv[e];
#pragma unroll
      for (int j = 0; j < 4; ++j) {
        float gp = accg[mi][ni][j] + bgv;
        float vp = accv[mi][ni][j] + bvv;
        float sg = 1.0f / (1.0f + __expf(-gp));
        float uu = (2.0f * sg - 1.0f) * vp;
        psum[ni] += uu;
        u[(rbase + j) * DD + e] = f2bf(uu);
      }
    }
#pragma unroll
  for (int ni = 0; ni < 2; ++ni) {
    psum[ni] += __shfl_xor(psum[ni], 16);
    psum[ni] += __shfl_xor(psum[ni], 32);
  }
  if (lane < 16) {
    int b = (int)(m0 >> 13);
    int ch = (int)((m0 & 8191) >> 7) + wm;
    size_t sidx = ((size_t)(b * NCHUNK + ch)) * DD + n0 + wn * 32 + lane;
    sums[sidx]      = psum[0];
    sums[sidx + 16] = psum[1];
  }
}

// ---------------- kernel 5: exclusive scan over chunk sums (in place) ------
__global__ __launch_bounds__(256) void scan_chunks(float* __restrict__ sums) {
  int b = blockIdx.x >> 2;
  int e = (blockIdx.x & 3) * 256 + threadIdx.x;
  float vals[NCHUNK];
#pragma unroll
  for (int c = 0; c < NCHUNK; ++c)
    vals[c] = sums[((size_t)(b * NCHUNK + c)) * DD + e];
  float carry = 0.f;
#pragma unroll
  for (int c = 0; c < NCHUNK; ++c) {
    float t = vals[c]; vals[c] = carry; carry += t;
  }
#pragma unroll
  for (int c = 0; c < NCHUNK; ++c)
    sums[((size_t)(b * NCHUNK + c)) * DD + e] = vals[c];
}

// ---------------- kernel 6: chunk-local scan + decay, in place ----------------
__global__ __launch_bounds__(128) void scan_final(
    unsigned short* __restrict__ u, const float* __restrict__ sums,
    const float* __restrict__ log_decay) {
  int bid = blockIdx.x;
  int half = bid & 1, chunk = (bid >> 1) & 63, b = bid >> 7;
  int e0 = half * 512 + threadIdx.x * 4;
  float alpha = log1pf(__expf(log_decay[0]));   // softplus
  float4 c = *(const float4*)(sums + ((size_t)(b * NCHUNK + chunk)) * DD + e0);
  size_t base = ((size_t)b * TT + (size_t)chunk * CLEN) * DD + e0;
#pragma unroll 4
  for (int i = 0; i < CLEN; ++i) {
    int t = chunk * CLEN + i;
    float dec = __expf(-alpha * (float)t);
    ushort4 w = *(const ushort4*)(u + base + (size_t)i * DD);
    c.x += bf2f(w.x); c.y += bf2f(w.y); c.z += bf2f(w.z); c.w += bf2f(w.w);
    ushort4 o;
    o.x = f2bf(c.x * dec); o.y = f2bf(c.y * dec);
    o.z = f2bf(c.z * dec); o.w = f2bf(c.w * dec);
    *(ushort4*)(u + base + (size_t)i * DD) = o;
  }
}

// ---------------- kernel 7: output GEMM + residual ----------------
// 256x256 tile, BK=64, 8 waves (2M x 4N), wave owns 128x64. Same skeleton.
// out[m,e] = x[m,e] + bo[e] + sum_d c[m,d]*Wo[e,d]
__global__ __launch_bounds__(512, 2) void gemm_out(
    const unsigned short* __restrict__ cmat, const unsigned short* __restrict__ wo,
    const float* __restrict__ bo, const float* __restrict__ x,
    float* __restrict__ out) {
  __shared__ unsigned short As[2][2][256 * 32];   // 64 KiB
  __shared__ unsigned short Bs[2][2][256 * 32];   // 64 KiB
  int tid = threadIdx.x, lane = tid & 63, wid = tid >> 6;
  int wm = wid >> 2, wn = wid & 3;         // 2 M-groups x 4 N-groups
  int nwg = gridDim.x;                     // 512, %8==0
  int swz = (blockIdx.x & 7) * (nwg >> 3) + (blockIdx.x >> 3);
  int bx = swz >> 2;                       // M block (128); by fastest
  int by = swz & 3;                        // N block (4)
  size_t m0 = (size_t)bx * 256;
  int n0 = by * 256;

  int rowq = tid >> 2, sp = tid & 3;
  int sl0 = sp ^ SWZ(rowq);
  const unsigned short* eA0 = cmat + (m0 + rowq) * DD + sl0 * 8;
  const unsigned short* eA1 = cmat + (m0 + 128 + rowq) * DD + sl0 * 8;
  const unsigned short* eB0 = wo + ((size_t)n0 + rowq) * DD + sl0 * 8;
  const unsigned short* eB1 = wo + ((size_t)n0 + 128 + rowq) * DD + sl0 * 8;

  auto SA = [&](int h) {
    char* d = (char*)&As[(h >> 1) & 1][h & 1][0] + tid * 16;
    gload16(eA0 + h * 32, d);
    gload16(eA1 + h * 32, d + 8192);
  };
  auto SB = [&](int h) {
    char* d = (char*)&Bs[(h >> 1) & 1][h & 1][0] + tid * 16;
    gload16(eB0 + h * 32, d);
    gload16(eB1 + h * 32, d + 8192);
  };

  f32x4 acc[8][4];
#pragma unroll
  for (int a = 0; a < 8; ++a)
#pragma unroll
    for (int b = 0; b < 4; ++b) acc[a][b] = (f32x4){0.f, 0.f, 0.f, 0.f};

  SA(0); SB(0); SA(1); SB(1);
  VMCNT4;
  BAR;

  int r = lane & 15, q = lane >> 4;
  for (int t = 0; t < NK2; ++t) {
    int buf = t & 1;
    bool more = (t + 1 < NK2);
    bf16x8 af[8], b0, b1;
    // ---- p0: kh0, n-halves 0,1 ----
    b0 = ldsfrag(Bs[buf][0], wn * 64 + r, q);
    b1 = ldsfrag(Bs[buf][0], wn * 64 + 16 + r, q);
#pragma unroll
    for (int mi = 0; mi < 8; ++mi)
      af[mi] = ldsfrag(As[buf][0], wm * 128 + mi * 16 + r, q);
    if (more) SA(2 * t + 2);
    BAR;
    __builtin_amdgcn_s_setprio(1);
#pragma unroll
    for (int mi = 0; mi < 8; ++mi) {
      acc[mi][0] = MFMA16(af[mi], b0, acc[mi][0]);
      acc[mi][1] = MFMA16(af[mi], b1, acc[mi][1]);
    }
    __builtin_amdgcn_s_setprio(0);
    BAR;
    // ---- p1: kh0, n-halves 2,3 (A reused) ----
    b0 = ldsfrag(Bs[buf][0], wn * 64 + 32 + r, q);
    b1 = ldsfrag(Bs[buf][0], wn * 64 + 48 + r, q);
    if (more) SB(2 * t + 2);
    BAR;
    __builtin_amdgcn_s_setprio(1);
#pragma unroll
    for (int mi = 0; mi < 8; ++mi) {
      acc[mi][2] = MFMA16(af[mi], b0, acc[mi][2]);
      acc[mi][3] = MFMA16(af[mi], b1, acc[mi][3]);
    }
    __builtin_amdgcn_s_setprio(0);
    if (more) VMCNT4; else VMCNT0;
    BAR;
    // ---- p2: kh1, n-halves 0,1 ----
    b0 = ldsfrag(Bs[buf][1], wn * 64 + r, q);
    b1 = ldsfrag(Bs[buf][1], wn * 64 + 16 + r, q);
#pragma unroll
    for (int mi = 0; mi < 8; ++mi)
      af[mi] = ldsfrag(As[buf][1], wm * 128 + mi * 16 + r, q);
    if (more) SA(2 * t + 3);
    BAR;
    __builtin_amdgcn_s_setprio(1);
#pragma unroll
    for (int mi = 0; mi < 8; ++mi) {
      acc[mi][0] = MFMA16(af[mi], b0, acc[mi][0]);
      acc[mi][1] = MFMA16(af[mi], b1, acc[mi][1]);
    }
    __builtin_amdgcn_s_setprio(0);
    BAR;
    // ---- p3: kh1, n-halves 2,3 (A reused) ----
    b0 = ldsfrag(Bs[buf][1], wn * 64 + 32 + r, q);
    b1 = ldsfrag(Bs[buf][1], wn * 64 + 48 + r, q);
    if (more) SB(2 * t + 3);
    BAR;
    __builtin_amdgcn_s_setprio(1);
#pragma unroll
    for (int mi = 0; mi < 8; ++mi) {
      acc[mi][2] = MFMA16(af[mi], b0, acc[mi][2]);
      acc[mi][3] = MFMA16(af[mi], b1, acc[mi][3]);
    }
    __builtin_amdgcn_s_setprio(0);
    if (more) VMCNT4;
    BAR;
  }

#pragma unroll
  for (int mi = 0; mi < 8; ++mi)
#pragma unroll
    for (int nq = 0; nq < 4; ++nq) {
      int e = n0 + wn * 64 + nq * 16 + r;
      size_t rbase = m0 + wm * 128 + mi * 16 + q * 4;
      float bov = bo[e];
#pragma unroll
      for (int j = 0; j < 4; ++j) {
        size_t idx = (rbase + j) * DD + e;
        out[idx] = x[idx] + bov + acc[mi][nq][j];
      }
    }
}

// ---------------- launch ----------------
extern "C" void kernel_launch(void* const* d_in, const int* in_sizes, int n_in,
                              void* d_out, int out_size, void* d_ws, size_t ws_size,
                              hipStream_t stream) {
  const float* x     = (const float*)d_in[0];
  const float* gamma = (const float*)d_in[1];
  const float* beta  = (const float*)d_in[2];
  const float* Wg    = (const float*)d_in[3];
  const float* bg    = (const float*)d_in[4];
  const float* Wv    = (const float*)d_in[5];
  const float* bv    = (const float*)d_in[6];
  const float* Wo    = (const float*)d_in[7];
  const float* bo    = (const float*)d_in[8];
  const float* ldcy  = (const float*)d_in[9];
  float* out = (float*)d_out;

  char* ws = (char*)d_ws;
  // layout: normed bf16 (64MiB) | u/c bf16 (64MiB) | Wg,Wv,Wo bf16 (3x2MiB) | sums f32 (1MiB)
  unsigned short* normed = (unsigned short*)ws;
  unsigned short* u      = (unsigned short*)(ws + (size_t)67108864);
  unsigned short* wgb    = (unsigned short*)(ws + (size_t)134217728);
  unsigned short* wvb    = wgb + 1048576;
  unsigned short* wob    = wvb + 1048576;
  float* sums            = (float*)(ws + (size_t)134217728 + (size_t)3 * 2097152);

  cast_weights<<<3072, 256, 0, stream>>>(Wg, Wv, Wo, wgb, wvb, wob);
  ln_kernel<<<MM, 256, 0, stream>>>(x, gamma, beta, normed);
  gemm_gv<<<dim3(MM / 256 * (DD / 128)), 512, 0, stream>>>(normed, wgb, wvb, bg, bv, u, sums);
  scan_chunks<<<BB * (DD / 256), 256, 0, stream>>>(sums);
  scan_final<<<BB * NCHUNK * 2, 128, 0, stream>>>(u, sums, ldcy);
  gemm_out<<<dim3(MM / 256 * (DD / 256)), 512, 0, stream>>>(u, wob, bo, x, out);
}